// Round 9
// baseline (184.295 us; speedup 1.0000x reference)
//
#include <hip/hip_runtime.h>
#include <hip/hip_bf16.h>

// Problem constants
#define B_ 8
#define T_ 1024
#define E_ 768
#define H_ 12
#define DH_ 64
#define E3_ 2304
#define M_ (B_ * T_)           // 8192 rows
// SCALE * log2(e): p = exp2(s * 0.125 * 1.4426950408889634)
// Applied to Q in gemm288's epilogue, NOT in the attention kernel.
#define SCALE_LOG2E 0.18033688011112042f

typedef __attribute__((ext_vector_type(8))) short short8;
typedef __attribute__((ext_vector_type(4))) float float4_;
typedef __attribute__((ext_vector_type(4))) unsigned short ushort4_;

__device__ __forceinline__ unsigned short f2bf(float f) {
    union { float f; unsigned int u; } v; v.f = f;
    unsigned int r = v.u + 0x7fffu + ((v.u >> 16) & 1u);
    return (unsigned short)(r >> 16);
}

// packed f32x2 -> bf16x2 (v_cvt_pk_bf16_f32, RNE — bit-identical to f2bf)
__device__ __forceinline__ unsigned int pk_bf16(float a, float b) {
    float2 t; t.x = a; t.y = b;
    union { __hip_bfloat162 h; unsigned int u; } cv;
    cv.h = __float22bfloat162_rn(t);
    return cv.u;
}

// async global->LDS, 16B per lane. LDS dest must be wave-uniform base + lane*16.
__device__ __forceinline__ void gld_lds16(const unsigned short* g, unsigned short* l) {
    __builtin_amdgcn_global_load_lds(
        (const __attribute__((address_space(1))) void*)g,
        (__attribute__((address_space(3))) void*)l,
        16, 0, 0);
}

// ---------------------------------------------------------------------------
// prep: one kernel for all prepasses (unchanged).
// ---------------------------------------------------------------------------
__global__ __launch_bounds__(256) void prep(const float* __restrict__ hs,
                                            const float* __restrict__ qkv_w,
                                            const float* __restrict__ proj_w,
                                            unsigned short* __restrict__ hs_bf,
                                            unsigned short* __restrict__ qkvwT,
                                            unsigned short* __restrict__ projwT) {
    __shared__ float tile[32][33];
    const int id = blockIdx.x;
    const int tid = threadIdx.x;
    if (id < 6144) {
        const int i = (id * 256 + tid) * 4;
        float4_ v = *(const float4_*)(hs + i);
        ushort4_ o;
        o.x = f2bf(v.x); o.y = f2bf(v.y); o.z = f2bf(v.z); o.w = f2bf(v.w);
        *(ushort4_*)(hs_bf + i) = o;
        return;
    }
    const float* W; unsigned short* Wt; int N, bx, by;
    if (id < 6144 + 1728) {
        const int t = id - 6144; W = qkv_w; Wt = qkvwT; N = E3_;
        bx = t % 72; by = t / 72;
    } else {
        const int t = id - 7872; W = proj_w; Wt = projwT; N = E_;
        bx = t % 24; by = t / 24;
    }
    const int k0 = by * 32, n0 = bx * 32;
    const int tx = tid & 31, ty = tid >> 5;
    for (int i = ty; i < 32; i += 8)
        tile[i][tx] = W[(size_t)(k0 + i) * N + n0 + tx];
    __syncthreads();
    for (int i = ty; i < 32; i += 8)
        Wt[(size_t)(n0 + i) * E_ + k0 + tx] = f2bf(tile[tx][i]);
}

// ---------------------------------------------------------------------------
// 256x288 3-phase GEMM for the QKV projection (unchanged — proven, R2-R8).
// Grid = 256 blocks = 1/CU, single dispatch round.
// ---------------------------------------------------------------------------
__global__ __launch_bounds__(512, 2) void gemm288(const unsigned short* __restrict__ A,
                                                  const unsigned short* __restrict__ Wt,
                                                  const float* __restrict__ bias,
                                                  unsigned short* __restrict__ mixedOut,
                                                  unsigned short* __restrict__ Vt) {
    const int K = 768;
    const int NT = 12;                 // K / 64
    __shared__ __align__(16) unsigned short lds[70144]; // A:2*16384 | B:2*18432 | scratch:512

    const int tid = threadIdx.x;
    const int lane = tid & 63;
    const int w = tid >> 6;            // 0..7
    const int quad = lane >> 4;
    const int l16 = lane & 15;
    const int wM = w >> 1;             // 0..3 (64-row slice)
    const int wN = w & 1;              // 0..1 (144-col slice)

    // grid 256 = 8 xcd * (8 bx * 4 byl), byl innermost
    const int id = blockIdx.x;
    const int xcd = id & 7;
    const int slot = id >> 3;          // 0..31
    const int bx = slot >> 2;          // 0..7
    const int byl = slot & 3;
    const int bm = (xcd * 4 + byl) * 256;
    const int bn = bx * 288;

    // ---- B granule ownership, sorted by nh third (wave-uniform) ----
    const int j4 = (w < 4) ? (w + 32) : 36;
    int kk0 = ((w % 18) / 6) * 64 + w;
    int kk1 = (((w + 8) % 18) / 6) * 64 + (w + 8);
    int kk2 = (((w + 16) % 18) / 6) * 64 + (w + 16);
    int kk3 = (((w + 24) % 18) / 6) * 64 + (w + 24);
    int kk4 = (j4 >= 36) ? (3 * 64 + 36) : (((j4 % 18) / 6) * 64 + j4);
#define CS_(a, b) { int _lo = min(a, b), _hi = max(a, b); a = _lo; b = _hi; }
    CS_(kk0, kk1) CS_(kk3, kk4) CS_(kk2, kk4) CS_(kk2, kk3) CS_(kk1, kk4)
    CS_(kk0, kk3) CS_(kk0, kk2) CS_(kk1, kk3) CS_(kk1, kk2)
#undef CS_
    const int b0 = kk0 & 63, b1 = kk1 & 63, b2 = kk2 & 63, b3 = kk3 & 63, b4 = kk4 & 63;

    // ---- staging constants ----
    const int srcrow = lane >> 3;                               // row within granule
    const int ssw = ((lane & 7) ^ (srcrow & 7)) << 3;           // swizzled src chunk (elems)
    const unsigned short* gaL = A + (size_t)(bm + srcrow) * K + ssw;
    const unsigned short* gbL = Wt + (size_t)(bn + srcrow) * K + ssw;
    unsigned short* ldsl = lds + lane * 8;

    // ---- fragment-read constants ----
    const int rsw0 = ((quad) ^ (l16 & 7)) << 3;                 // ks=0
    const int rsw1 = ((quad + 4) ^ (l16 & 7)) << 3;             // ks=1
    const unsigned short* rdA = lds + (wM * 64 + l16) * 64;
    const unsigned short* rdB = lds + 32768 + (wN * 144 + l16) * 64;

    short8 aF[4][2], bF[3][2];
    float4_ acc[4][9] = {};

#define STA_(aj, toff, bufA) gld_lds16(gaL + (size_t)(aj) * 6144 + (toff), (bufA) + (aj) * 512)
#define STB_(j, toff, bufB) { \
    const int _j = (j); \
    const unsigned short* _s = gbL + (size_t)(_j >= 36 ? 0 : _j) * 6144 + (toff); \
    unsigned short* _d = (_j >= 36) ? (ldsl + 69632) : ((bufB) + _j * 512); \
    gld_lds16(_s, _d); }

#define LDA_(buf) { \
    const unsigned short* _a = rdA + (buf) * 16384; \
    aF[0][0] = *(const short8*)(_a + rsw0);        aF[0][1] = *(const short8*)(_a + rsw1); \
    aF[1][0] = *(const short8*)(_a + 1024 + rsw0); aF[1][1] = *(const short8*)(_a + 1024 + rsw1); \
    aF[2][0] = *(const short8*)(_a + 2048 + rsw0); aF[2][1] = *(const short8*)(_a + 2048 + rsw1); \
    aF[3][0] = *(const short8*)(_a + 3072 + rsw0); aF[3][1] = *(const short8*)(_a + 3072 + rsw1); }

#define LDB_(buf, nh) { \
    const unsigned short* _b = rdB + (buf) * 18432 + (nh) * 3072; \
    bF[0][0] = *(const short8*)(_b + rsw0);        bF[0][1] = *(const short8*)(_b + rsw1); \
    bF[1][0] = *(const short8*)(_b + 1024 + rsw0); bF[1][1] = *(const short8*)(_b + 1024 + rsw1); \
    bF[2][0] = *(const short8*)(_b + 2048 + rsw0); bF[2][1] = *(const short8*)(_b + 2048 + rsw1); }

#define MMA_(nh) \
    __builtin_amdgcn_s_setprio(1); \
    _Pragma("unroll") for (int mt = 0; mt < 4; ++mt) \
    _Pragma("unroll") for (int nt = 0; nt < 3; ++nt) { \
        acc[mt][(nh) * 3 + nt] = __builtin_amdgcn_mfma_f32_16x16x32_bf16( \
            aF[mt][0], bF[nt][0], acc[mt][(nh) * 3 + nt], 0, 0, 0); \
        acc[mt][(nh) * 3 + nt] = __builtin_amdgcn_mfma_f32_16x16x32_bf16( \
            aF[mt][1], bF[nt][1], acc[mt][(nh) * 3 + nt], 0, 0, 0); } \
    __builtin_amdgcn_s_setprio(0);

#define BARRIER_ __builtin_amdgcn_s_barrier()
#define WLGKM0_ { asm volatile("s_waitcnt lgkmcnt(0)" ::: "memory"); __builtin_amdgcn_sched_barrier(0); }
#define WVM3_ asm volatile("s_waitcnt vmcnt(3)" ::: "memory")
#define WVM0_ asm volatile("s_waitcnt vmcnt(0)" ::: "memory")

    // ---- prologue: stage tile 0 (A first, then nh-sorted B; dummies last) ----
    {
        unsigned short* bufA = ldsl;            // buf0 A
        unsigned short* bufB = ldsl + 32768;    // buf0 B
        STA_(w, 0, bufA); STA_(w + 8, 0, bufA); STA_(w + 16, 0, bufA); STA_(w + 24, 0, bufA);
        STB_(b0, 0, bufB); STB_(b1, 0, bufB); STB_(b2, 0, bufB); STB_(b3, 0, bufB); STB_(b4, 0, bufB);
    }
    WVM3_; BARRIER_;

#pragma unroll 1
    for (int t = 0; t < NT - 1; ++t) {
        const int buf = t & 1;
        const int toff = (t + 1) * 64;
        unsigned short* bufA = ldsl + (buf ^ 1) * 16384;
        unsigned short* bufB = ldsl + 32768 + (buf ^ 1) * 18432;

        // phase 0 (nh=0)
        LDA_(buf); LDB_(buf, 0);
        STA_(w, toff, bufA); STA_(w + 8, toff, bufA); STA_(w + 16, toff, bufA);
        BARRIER_; WLGKM0_; MMA_(0);
        WVM3_; BARRIER_;
        // phase 1 (nh=1)
        LDB_(buf, 1);
        STA_(w + 24, toff, bufA); STB_(b0, toff, bufB); STB_(b1, toff, bufB);
        BARRIER_; WLGKM0_; MMA_(1);
        WVM3_; BARRIER_;
        // phase 2 (nh=2)
        LDB_(buf, 2);
        STB_(b2, toff, bufB); STB_(b3, toff, bufB); STB_(b4, toff, bufB);
        BARRIER_; WLGKM0_; MMA_(2);
        WVM3_; BARRIER_;
    }
    // ---- peeled last tile (t = NT-1 = 11, buf = 1): no stages ----
    {
        LDA_(1); LDB_(1, 0);
        BARRIER_; WLGKM0_; MMA_(0);
        WVM0_; BARRIER_;          // drain phase2(NT-2) stages before nh1/nh2 reads
        LDB_(1, 1);
        BARRIER_; WLGKM0_; MMA_(1);
        BARRIER_;
        LDB_(1, 2);
        BARRIER_; WLGKM0_; MMA_(2);
    }
#undef STA_
#undef STB_
#undef LDA_
#undef LDB_
#undef MMA_

    // ---- epilogue ----
    // row = bm + wM*64 + mt*16 + quad*4 + i ; col = bn + wN*144 + ntg*16 + l16
    const int bb = bm >> 10;
    const int tloc = (bm & 1023) + wM * 64;
#pragma unroll
    for (int ntg = 0; ntg < 9; ++ntg) {
        const int col = bn + wN * 144 + ntg * 16 + l16;
        const float bv = bias[col];
        if (col >= 1536) {
            // V -> Vt[(b*12+h)*64 + d][1024], transposed
            const int n = col - 1536;
            const int h = n >> 6, d = n & 63;
            const size_t vrow = (size_t)((bb * H_ + h) * 64 + d) * T_;
#pragma unroll
            for (int mt = 0; mt < 4; ++mt) {
                uint2 pk;
                pk.x = pk_bf16(acc[mt][ntg][0] + bv, acc[mt][ntg][1] + bv);
                pk.y = pk_bf16(acc[mt][ntg][2] + bv, acc[mt][ntg][3] + bv);
                *(uint2*)(Vt + vrow + tloc + mt * 16 + quad * 4) = pk;
            }
        } else {
            const float qs = (col < 768) ? SCALE_LOG2E : 1.0f;
#pragma unroll
            for (int mt = 0; mt < 4; ++mt) {
#pragma unroll
                for (int i = 0; i < 4; ++i) {
                    const int row = bm + wM * 64 + mt * 16 + quad * 4 + i;
                    mixedOut[(size_t)row * E3_ + col] = f2bf((acc[mt][ntg][i] + bv) * qs);
                }
            }
        }
    }
}

// ---------------------------------------------------------------------------
// proj96: output projection, 256x96 exact-fill 3-phase (unchanged from R8).
// ---------------------------------------------------------------------------
__global__ __launch_bounds__(512, 2) void proj96(const unsigned short* __restrict__ A,
                                                 const unsigned short* __restrict__ Wt,
                                                 const float* __restrict__ bias,
                                                 float* __restrict__ out) {
    const int K = 768;
    const int NT = 12;
    __shared__ __align__(16) unsigned short lds[45568]; // A:2*16384 | B:2*6144 | scratch:512

    const int tid = threadIdx.x;
    const int lane = tid & 63;
    const int w = tid >> 6;            // 0..7
    const int quad = lane >> 4;
    const int l16 = lane & 15;
    const int wM = w >> 1;             // 0..3 (64-row slice)
    const int wN = w & 1;              // 0..1 (48-col slice)

    const int id = blockIdx.x;
    const int xcd = id & 7;
    const int slot = id >> 3;
    const int bx = slot >> 2;          // 0..7  (N tile, 96 cols)
    const int byl = slot & 3;
    const int bm = (xcd * 4 + byl) * 256;
    const int bn = bx * 96;

    const int jB2 = (w < 4) ? (8 + w) : -1;   // second B granule (or dummy)

    const int srcrow = lane >> 3;
    const int ssw = ((lane & 7) ^ (srcrow & 7)) << 3;
    const unsigned short* gaL = A + (size_t)(bm + srcrow) * K + ssw;
    const unsigned short* gbL = Wt + (size_t)(bn + srcrow) * K + ssw;
    unsigned short* ldsl = lds + lane * 8;

    const int rsw0 = ((quad) ^ (l16 & 7)) << 3;
    const int rsw1 = ((quad + 4) ^ (l16 & 7)) << 3;
    const unsigned short* rdA = lds + (wM * 64 + l16) * 64;
    const unsigned short* rdB = lds + 32768 + (wN * 48 + l16) * 64;

    short8 aF[4][2], bF[2];
    float4_ acc[4][3] = {};

#define PSTA(aj, toff, nb) gld_lds16(gaL + (size_t)(aj) * 6144 + (toff), \
                                     ldsl + (nb) * 16384 + (aj) * 512)
#define PSTB(j, toff, nb) { \
    const int _j = (j); \
    const unsigned short* _s = gbL + (size_t)(_j < 0 ? 0 : _j) * 6144 + (toff); \
    unsigned short* _d = (_j < 0) ? (ldsl + 45056) : (ldsl + 32768 + (nb) * 6144 + _j * 512); \
    gld_lds16(_s, _d); }
#define PLDA(buf) { \
    const unsigned short* _a = rdA + (buf) * 16384; \
    aF[0][0] = *(const short8*)(_a + rsw0);        aF[0][1] = *(const short8*)(_a + rsw1); \
    aF[1][0] = *(const short8*)(_a + 1024 + rsw0); aF[1][1] = *(const short8*)(_a + 1024 + rsw1); \
    aF[2][0] = *(const short8*)(_a + 2048 + rsw0); aF[2][1] = *(const short8*)(_a + 2048 + rsw1); \
    aF[3][0] = *(const short8*)(_a + 3072 + rsw0); aF[3][1] = *(const short8*)(_a + 3072 + rsw1); }
#define PLDB(buf, nt_) { \
    const unsigned short* _b = rdB + (buf) * 6144 + (nt_) * 1024; \
    bF[0] = *(const short8*)(_b + rsw0); \
    bF[1] = *(const short8*)(_b + rsw1); }
#define PMMA(nt_) \
    __builtin_amdgcn_s_setprio(1); \
    _Pragma("unroll") for (int mt = 0; mt < 4; ++mt) { \
        acc[mt][nt_] = __builtin_amdgcn_mfma_f32_16x16x32_bf16(aF[mt][0], bF[0], acc[mt][nt_], 0, 0, 0); \
        acc[mt][nt_] = __builtin_amdgcn_mfma_f32_16x16x32_bf16(aF[mt][1], bF[1], acc[mt][nt_], 0, 0, 0); } \
    __builtin_amdgcn_s_setprio(0);
#define PBAR __builtin_amdgcn_s_barrier()
#define PLGKM0 { asm volatile("s_waitcnt lgkmcnt(0)" ::: "memory"); __builtin_amdgcn_sched_barrier(0); }

    PSTA(w, 0, 0); PSTA(w + 8, 0, 0); PSTA(w + 16, 0, 0); PSTA(w + 24, 0, 0);
    PSTB(w, 0, 0); PSTB(jB2, 0, 0);
    asm volatile("s_waitcnt vmcnt(0)" ::: "memory");
    PBAR;

#pragma unroll 1
    for (int t = 0; t < NT - 1; ++t) {
        const int buf = t & 1;
        const int nb = buf ^ 1;
        const int toff = (t + 1) * 64;

        PLDA(buf); PLDB(buf, 0);
        PSTA(w, toff, nb); PSTA(w + 8, toff, nb); PSTA(w + 16, toff, nb);
        PBAR; PLGKM0; PMMA(0);
        asm volatile("s_waitcnt vmcnt(3)" ::: "memory"); PBAR;
        PLDB(buf, 1);
        PSTA(w + 24, toff, nb); PSTB(w, toff, nb); PSTB(jB2, toff, nb);
        PBAR; PLGKM0; PMMA(1);
        asm volatile("s_waitcnt vmcnt(3)" ::: "memory"); PBAR;
        PLDB(buf, 2);
        PBAR; PLGKM0; PMMA(2);
        asm volatile("s_waitcnt vmcnt(0)" ::: "memory"); PBAR;
    }
    {
        PLDA(1);
        PLDB(1, 0); PLGKM0; PMMA(0);
        PLDB(1, 1); PLGKM0; PMMA(1);
        PLDB(1, 2); PLGKM0; PMMA(2);
    }
#undef PSTA
#undef PSTB
#undef PLDA
#undef PLDB
#undef PMMA
#undef PBAR
#undef PLGKM0

#pragma unroll
    for (int nt = 0; nt < 3; ++nt) {
        const int col = bn + wN * 48 + nt * 16 + l16;
        const float bv = bias[col];
#pragma unroll
        for (int mt = 0; mt < 4; ++mt) {
#pragma unroll
            for (int i = 0; i < 4; ++i) {
                const int row = bm + wM * 64 + mt * 16 + quad * 4 + i;
                out[(size_t)row * E_ + col] = acc[mt][nt][i] + bv;
            }
        }
    }
}

// ---------------------------------------------------------------------------
// MFMA flash attention v11: R6 structure with Q-TILE 64 for 2x occupancy.
// R8 counters: VALU 40% / MFMA 22% / ~38% stall at 3 blocks/CU (grid 768)
// — TLP-starved. Q-tile 128->64: grid dim3(96,16) = 1536 blocks = 6/CU =
// 24 waves/CU. Wave = 16 q rows (hh dim removed — pure simplification;
// per-q-row FLOP order unchanged -> bit-identical output). K/V staging per
// block unchanged (2x chip-wide, L2-served; 96 = 0 mod 8 keeps each head's
// K/V on one XCD's L2). LDS 25.9 KB -> 6 blocks fit (155/160 KB).
// __launch_bounds__(256,6) caps VGPR at 85 so occupancy is grid/LDS-bound.
// ---------------------------------------------------------------------------
__global__ __launch_bounds__(256, 6) void attn_mfma(const unsigned short* __restrict__ mixed,
                                                    const unsigned short* __restrict__ Vt,
                                                    unsigned short* __restrict__ ctx) {
    const int bh = blockIdx.x;
    const int b = bh / H_;
    const int h = bh % H_;
    const int q0 = blockIdx.y * 64;
    const int tid = threadIdx.x;
    const int lane = tid & 63;
    const int w = tid >> 6;
    const int quad = lane >> 4;
    const int l16 = lane & 15;

    __shared__ __align__(16) unsigned short Kl[8 * 520];
    __shared__ __align__(16) unsigned short Vl[8 * 520];
    __shared__ __align__(16) unsigned short Pl[4][16 * 72];
    unsigned short* pw = &Pl[w][0];

    // Q fragments: wave w covers q rows q0 + w*16 .. +15
    short8 qf[2];
    {
        const size_t qrow = (size_t)(b * T_ + q0 + w * 16 + l16) * E3_ + h * 64;
        qf[0] = *(const short8*)(mixed + qrow + quad * 8);
        qf[1] = *(const short8*)(mixed + qrow + 32 + quad * 8);
    }

    float4_ o[4] = {};               // O C-frags [d-tile]
    float lps = 0.0f;                // per-thread row-sum (q = l16)

    const size_t kbase = (size_t)(b * T_) * E3_ + E_ + h * 64;
    const size_t vtb = (size_t)bh * 64 * T_;

    const int srow = tid >> 3;
    const int sc = tid & 7;

    short8 k1 = *(const short8*)(mixed + kbase + (size_t)srow * E3_ + sc * 8);
    short8 k2 = *(const short8*)(mixed + kbase + (size_t)(srow + 32) * E3_ + sc * 8);
    short8 v1 = *(const short8*)(Vt + vtb + (size_t)srow * T_ + sc * 8);
    short8 v2 = *(const short8*)(Vt + vtb + (size_t)(srow + 32) * T_ + sc * 8);

    for (int kv0 = 0; kv0 < T_; kv0 += 64) {
        __syncthreads();
        *(short8*)(&Kl[sc * 520 + srow * 8]) = k1;
        *(short8*)(&Kl[sc * 520 + (srow + 32) * 8]) = k2;
        *(short8*)(&Vl[sc * 520 + srow * 8]) = v1;
        *(short8*)(&Vl[sc * 520 + (srow + 32) * 8]) = v2;
        __syncthreads();

        if (kv0 + 64 < T_) {
            const int kn = kv0 + 64;
            k1 = *(const short8*)(mixed + kbase + (size_t)(kn + srow) * E3_ + sc * 8);
            k2 = *(const short8*)(mixed + kbase + (size_t)(kn + srow + 32) * E3_ + sc * 8);
            v1 = *(const short8*)(Vt + vtb + (size_t)srow * T_ + kn + sc * 8);
            v2 = *(const short8*)(Vt + vtb + (size_t)(srow + 32) * T_ + kn + sc * 8);
        }

        // S^T = K Q^T: thread holds key = nt*16 + quad*4 + i, q = l16
        float4_ st[4];
#pragma unroll
        for (int nt = 0; nt < 4; ++nt) {
            const int key = nt * 16 + l16;
            short8 kf0 = *(const short8*)(&Kl[quad * 520 + key * 8]);
            short8 kf1 = *(const short8*)(&Kl[(4 + quad) * 520 + key * 8]);
            float4_ z = {};
            z = __builtin_amdgcn_mfma_f32_16x16x32_bf16(kf0, qf[0], z, 0, 0, 0);
            st[nt] = __builtin_amdgcn_mfma_f32_16x16x32_bf16(kf1, qf[1], z, 0, 0, 0);
        }

        // p = exp2(s'); scalar row-sum; packed cvt -> ds_write_b64 per nt
#pragma unroll
        for (int nt = 0; nt < 4; ++nt) {
            const float p0 = __builtin_amdgcn_exp2f(st[nt][0]);
            const float p1 = __builtin_amdgcn_exp2f(st[nt][1]);
            const float p2 = __builtin_amdgcn_exp2f(st[nt][2]);
            const float p3 = __builtin_amdgcn_exp2f(st[nt][3]);
            uint2 pk;
            pk.x = pk_bf16(p0, p1);
            pk.y = pk_bf16(p2, p3);
            lps += (p0 + p1) + (p2 + p3);
            *(uint2*)(&pw[l16 * 72 + nt * 16 + quad * 4]) = pk;
        }

        // P A-frags (in-wave DS ordering; no barrier needed)
        short8 pf0 = *(const short8*)(&pw[l16 * 72 + quad * 8]);
        short8 pf1 = *(const short8*)(&pw[l16 * 72 + 32 + quad * 8]);

        // O += P V
#pragma unroll
        for (int dt = 0; dt < 4; ++dt) {
            const int d = dt * 16 + l16;
            short8 vf0 = *(const short8*)(&Vl[quad * 520 + d * 8]);
            short8 vf1 = *(const short8*)(&Vl[(4 + quad) * 520 + d * 8]);
            o[dt] = __builtin_amdgcn_mfma_f32_16x16x32_bf16(pf0, vf0, o[dt], 0, 0, 0);
            o[dt] = __builtin_amdgcn_mfma_f32_16x16x32_bf16(pf1, vf1, o[dt], 0, 0, 0);
        }
    }

    // finalize: l at q = l16, partials across 4 quad groups
    {
        float l = lps;
        l += __shfl_xor(l, 16, 64);
        l += __shfl_xor(l, 32, 64);
        float4_ inv;
#pragma unroll
        for (int i = 0; i < 4; ++i)
            inv[i] = 1.0f / __shfl(l, quad * 4 + i, 16);
#pragma unroll
        for (int dt = 0; dt < 4; ++dt) {
#pragma unroll
            for (int i = 0; i < 4; ++i) {
                const float v = o[dt][i] * inv[i];
                const size_t row = (size_t)(b * T_ + q0 + w * 16 + quad * 4 + i);
                ctx[row * E_ + h * 64 + dt * 16 + l16] = f2bf(v);
            }
        }
    }
}

// ---------------------------------------------------------------------------
extern "C" void kernel_launch(void* const* d_in, const int* in_sizes, int n_in,
                              void* d_out, int out_size, void* d_ws, size_t ws_size,
                              hipStream_t stream) {
    const float* hs     = (const float*)d_in[0];
    const float* qkv_w  = (const float*)d_in[1];
    const float* qkv_b  = (const float*)d_in[2];
    const float* proj_w = (const float*)d_in[3];
    const float* proj_b = (const float*)d_in[4];
    float* out = (float*)d_out;

    unsigned short* hs_bf  = (unsigned short*)d_ws;                 // [8192][768]
    unsigned short* qkvwT  = hs_bf + (size_t)M_ * E_;               // [2304][768]
    unsigned short* projwT = qkvwT + (size_t)E3_ * E_;              // [768][768]
    unsigned short* mixed  = projwT + (size_t)E_ * E_;              // [8192][2304]
    unsigned short* Vt     = mixed + (size_t)M_ * E3_;              // [96*64][1024]
    unsigned short* ctx    = hs_bf;  // alias: hs_bf dead after GEMM1

    // 0) fused prepasses: cast + both weight transposes
    prep<<<8448, 256, 0, stream>>>(hs, qkv_w, proj_w, hs_bf, qkvwT, projwT);

    // 1) QKV projection -> mixed (Q scaled, K bf16) + Vt (V transposed)
    gemm288<<<256, 512, 0, stream>>>(hs_bf, qkvwT, qkv_b, mixed, Vt);
    // 2) attention -> ctx (bf16)  [Q-tile 64, 1536 blocks = 6/CU]
    attn_mfma<<<dim3(B_ * H_, T_ / 64), 256, 0, stream>>>(mixed, Vt, ctx);
    // 3) output projection -> out (fp32), 256x96 exact-fill 3-phase
    proj96<<<256, 512, 0, stream>>>(ctx, projwT, proj_b, out);
}

// Round 10
// 177.177 us; speedup vs baseline: 1.0402x; 1.0402x over previous
//
#include <hip/hip_runtime.h>
#include <hip/hip_bf16.h>

// Problem constants
#define B_ 8
#define T_ 1024
#define E_ 768
#define H_ 12
#define DH_ 64
#define E3_ 2304
#define M_ (B_ * T_)           // 8192 rows
// SCALE * log2(e): p = exp2(s * 0.125 * 1.4426950408889634)
// Applied to Q in gemm288's epilogue, NOT in the attention kernel.
#define SCALE_LOG2E 0.18033688011112042f

typedef __attribute__((ext_vector_type(8))) short short8;
typedef __attribute__((ext_vector_type(4))) float float4_;
typedef __attribute__((ext_vector_type(4))) unsigned short ushort4_;

__device__ __forceinline__ unsigned short f2bf(float f) {
    union { float f; unsigned int u; } v; v.f = f;
    unsigned int r = v.u + 0x7fffu + ((v.u >> 16) & 1u);
    return (unsigned short)(r >> 16);
}

// packed f32x2 -> bf16x2 (v_cvt_pk_bf16_f32, RNE — bit-identical to f2bf)
__device__ __forceinline__ unsigned int pk_bf16(float a, float b) {
    float2 t; t.x = a; t.y = b;
    union { __hip_bfloat162 h; unsigned int u; } cv;
    cv.h = __float22bfloat162_rn(t);
    return cv.u;
}

// async global->LDS, 16B per lane. LDS dest must be wave-uniform base + lane*16.
__device__ __forceinline__ void gld_lds16(const unsigned short* g, unsigned short* l) {
    __builtin_amdgcn_global_load_lds(
        (const __attribute__((address_space(1))) void*)g,
        (__attribute__((address_space(3))) void*)l,
        16, 0, 0);
}

// ---------------------------------------------------------------------------
// prep: one kernel for all prepasses (unchanged).
// ---------------------------------------------------------------------------
__global__ __launch_bounds__(256) void prep(const float* __restrict__ hs,
                                            const float* __restrict__ qkv_w,
                                            const float* __restrict__ proj_w,
                                            unsigned short* __restrict__ hs_bf,
                                            unsigned short* __restrict__ qkvwT,
                                            unsigned short* __restrict__ projwT) {
    __shared__ float tile[32][33];
    const int id = blockIdx.x;
    const int tid = threadIdx.x;
    if (id < 6144) {
        const int i = (id * 256 + tid) * 4;
        float4_ v = *(const float4_*)(hs + i);
        ushort4_ o;
        o.x = f2bf(v.x); o.y = f2bf(v.y); o.z = f2bf(v.z); o.w = f2bf(v.w);
        *(ushort4_*)(hs_bf + i) = o;
        return;
    }
    const float* W; unsigned short* Wt; int N, bx, by;
    if (id < 6144 + 1728) {
        const int t = id - 6144; W = qkv_w; Wt = qkvwT; N = E3_;
        bx = t % 72; by = t / 72;
    } else {
        const int t = id - 7872; W = proj_w; Wt = projwT; N = E_;
        bx = t % 24; by = t / 24;
    }
    const int k0 = by * 32, n0 = bx * 32;
    const int tx = tid & 31, ty = tid >> 5;
    for (int i = ty; i < 32; i += 8)
        tile[i][tx] = W[(size_t)(k0 + i) * N + n0 + tx];
    __syncthreads();
    for (int i = ty; i < 32; i += 8)
        Wt[(size_t)(n0 + i) * E_ + k0 + tx] = f2bf(tile[tx][i]);
}

// ---------------------------------------------------------------------------
// 256x288 3-phase GEMM for the QKV projection (unchanged — proven, R2-R9).
// Grid = 256 blocks = 1/CU, single dispatch round.
// ---------------------------------------------------------------------------
__global__ __launch_bounds__(512, 2) void gemm288(const unsigned short* __restrict__ A,
                                                  const unsigned short* __restrict__ Wt,
                                                  const float* __restrict__ bias,
                                                  unsigned short* __restrict__ mixedOut,
                                                  unsigned short* __restrict__ Vt) {
    const int K = 768;
    const int NT = 12;                 // K / 64
    __shared__ __align__(16) unsigned short lds[70144]; // A:2*16384 | B:2*18432 | scratch:512

    const int tid = threadIdx.x;
    const int lane = tid & 63;
    const int w = tid >> 6;            // 0..7
    const int quad = lane >> 4;
    const int l16 = lane & 15;
    const int wM = w >> 1;             // 0..3 (64-row slice)
    const int wN = w & 1;              // 0..1 (144-col slice)

    // grid 256 = 8 xcd * (8 bx * 4 byl), byl innermost
    const int id = blockIdx.x;
    const int xcd = id & 7;
    const int slot = id >> 3;          // 0..31
    const int bx = slot >> 2;          // 0..7
    const int byl = slot & 3;
    const int bm = (xcd * 4 + byl) * 256;
    const int bn = bx * 288;

    // ---- B granule ownership, sorted by nh third (wave-uniform) ----
    const int j4 = (w < 4) ? (w + 32) : 36;
    int kk0 = ((w % 18) / 6) * 64 + w;
    int kk1 = (((w + 8) % 18) / 6) * 64 + (w + 8);
    int kk2 = (((w + 16) % 18) / 6) * 64 + (w + 16);
    int kk3 = (((w + 24) % 18) / 6) * 64 + (w + 24);
    int kk4 = (j4 >= 36) ? (3 * 64 + 36) : (((j4 % 18) / 6) * 64 + j4);
#define CS_(a, b) { int _lo = min(a, b), _hi = max(a, b); a = _lo; b = _hi; }
    CS_(kk0, kk1) CS_(kk3, kk4) CS_(kk2, kk4) CS_(kk2, kk3) CS_(kk1, kk4)
    CS_(kk0, kk3) CS_(kk0, kk2) CS_(kk1, kk3) CS_(kk1, kk2)
#undef CS_
    const int b0 = kk0 & 63, b1 = kk1 & 63, b2 = kk2 & 63, b3 = kk3 & 63, b4 = kk4 & 63;

    // ---- staging constants ----
    const int srcrow = lane >> 3;                               // row within granule
    const int ssw = ((lane & 7) ^ (srcrow & 7)) << 3;           // swizzled src chunk (elems)
    const unsigned short* gaL = A + (size_t)(bm + srcrow) * K + ssw;
    const unsigned short* gbL = Wt + (size_t)(bn + srcrow) * K + ssw;
    unsigned short* ldsl = lds + lane * 8;

    // ---- fragment-read constants ----
    const int rsw0 = ((quad) ^ (l16 & 7)) << 3;                 // ks=0
    const int rsw1 = ((quad + 4) ^ (l16 & 7)) << 3;             // ks=1
    const unsigned short* rdA = lds + (wM * 64 + l16) * 64;
    const unsigned short* rdB = lds + 32768 + (wN * 144 + l16) * 64;

    short8 aF[4][2], bF[3][2];
    float4_ acc[4][9] = {};

#define STA_(aj, toff, bufA) gld_lds16(gaL + (size_t)(aj) * 6144 + (toff), (bufA) + (aj) * 512)
#define STB_(j, toff, bufB) { \
    const int _j = (j); \
    const unsigned short* _s = gbL + (size_t)(_j >= 36 ? 0 : _j) * 6144 + (toff); \
    unsigned short* _d = (_j >= 36) ? (ldsl + 69632) : ((bufB) + _j * 512); \
    gld_lds16(_s, _d); }

#define LDA_(buf) { \
    const unsigned short* _a = rdA + (buf) * 16384; \
    aF[0][0] = *(const short8*)(_a + rsw0);        aF[0][1] = *(const short8*)(_a + rsw1); \
    aF[1][0] = *(const short8*)(_a + 1024 + rsw0); aF[1][1] = *(const short8*)(_a + 1024 + rsw1); \
    aF[2][0] = *(const short8*)(_a + 2048 + rsw0); aF[2][1] = *(const short8*)(_a + 2048 + rsw1); \
    aF[3][0] = *(const short8*)(_a + 3072 + rsw0); aF[3][1] = *(const short8*)(_a + 3072 + rsw1); }

#define LDB_(buf, nh) { \
    const unsigned short* _b = rdB + (buf) * 18432 + (nh) * 3072; \
    bF[0][0] = *(const short8*)(_b + rsw0);        bF[0][1] = *(const short8*)(_b + rsw1); \
    bF[1][0] = *(const short8*)(_b + 1024 + rsw0); bF[1][1] = *(const short8*)(_b + 1024 + rsw1); \
    bF[2][0] = *(const short8*)(_b + 2048 + rsw0); bF[2][1] = *(const short8*)(_b + 2048 + rsw1); }

#define MMA_(nh) \
    __builtin_amdgcn_s_setprio(1); \
    _Pragma("unroll") for (int mt = 0; mt < 4; ++mt) \
    _Pragma("unroll") for (int nt = 0; nt < 3; ++nt) { \
        acc[mt][(nh) * 3 + nt] = __builtin_amdgcn_mfma_f32_16x16x32_bf16( \
            aF[mt][0], bF[nt][0], acc[mt][(nh) * 3 + nt], 0, 0, 0); \
        acc[mt][(nh) * 3 + nt] = __builtin_amdgcn_mfma_f32_16x16x32_bf16( \
            aF[mt][1], bF[nt][1], acc[mt][(nh) * 3 + nt], 0, 0, 0); } \
    __builtin_amdgcn_s_setprio(0);

#define BARRIER_ __builtin_amdgcn_s_barrier()
#define WLGKM0_ { asm volatile("s_waitcnt lgkmcnt(0)" ::: "memory"); __builtin_amdgcn_sched_barrier(0); }
#define WVM3_ asm volatile("s_waitcnt vmcnt(3)" ::: "memory")
#define WVM0_ asm volatile("s_waitcnt vmcnt(0)" ::: "memory")

    // ---- prologue: stage tile 0 (A first, then nh-sorted B; dummies last) ----
    {
        unsigned short* bufA = ldsl;            // buf0 A
        unsigned short* bufB = ldsl + 32768;    // buf0 B
        STA_(w, 0, bufA); STA_(w + 8, 0, bufA); STA_(w + 16, 0, bufA); STA_(w + 24, 0, bufA);
        STB_(b0, 0, bufB); STB_(b1, 0, bufB); STB_(b2, 0, bufB); STB_(b3, 0, bufB); STB_(b4, 0, bufB);
    }
    WVM3_; BARRIER_;

#pragma unroll 1
    for (int t = 0; t < NT - 1; ++t) {
        const int buf = t & 1;
        const int toff = (t + 1) * 64;
        unsigned short* bufA = ldsl + (buf ^ 1) * 16384;
        unsigned short* bufB = ldsl + 32768 + (buf ^ 1) * 18432;

        // phase 0 (nh=0)
        LDA_(buf); LDB_(buf, 0);
        STA_(w, toff, bufA); STA_(w + 8, toff, bufA); STA_(w + 16, toff, bufA);
        BARRIER_; WLGKM0_; MMA_(0);
        WVM3_; BARRIER_;
        // phase 1 (nh=1)
        LDB_(buf, 1);
        STA_(w + 24, toff, bufA); STB_(b0, toff, bufB); STB_(b1, toff, bufB);
        BARRIER_; WLGKM0_; MMA_(1);
        WVM3_; BARRIER_;
        // phase 2 (nh=2)
        LDB_(buf, 2);
        STB_(b2, toff, bufB); STB_(b3, toff, bufB); STB_(b4, toff, bufB);
        BARRIER_; WLGKM0_; MMA_(2);
        WVM3_; BARRIER_;
    }
    // ---- peeled last tile (t = NT-1 = 11, buf = 1): no stages ----
    {
        LDA_(1); LDB_(1, 0);
        BARRIER_; WLGKM0_; MMA_(0);
        WVM0_; BARRIER_;          // drain phase2(NT-2) stages before nh1/nh2 reads
        LDB_(1, 1);
        BARRIER_; WLGKM0_; MMA_(1);
        BARRIER_;
        LDB_(1, 2);
        BARRIER_; WLGKM0_; MMA_(2);
    }
#undef STA_
#undef STB_
#undef LDA_
#undef LDB_
#undef MMA_

    // ---- epilogue ----
    // row = bm + wM*64 + mt*16 + quad*4 + i ; col = bn + wN*144 + ntg*16 + l16
    const int bb = bm >> 10;
    const int tloc = (bm & 1023) + wM * 64;
#pragma unroll
    for (int ntg = 0; ntg < 9; ++ntg) {
        const int col = bn + wN * 144 + ntg * 16 + l16;
        const float bv = bias[col];
        if (col >= 1536) {
            // V -> Vt[(b*12+h)*64 + d][1024], transposed
            const int n = col - 1536;
            const int h = n >> 6, d = n & 63;
            const size_t vrow = (size_t)((bb * H_ + h) * 64 + d) * T_;
#pragma unroll
            for (int mt = 0; mt < 4; ++mt) {
                uint2 pk;
                pk.x = pk_bf16(acc[mt][ntg][0] + bv, acc[mt][ntg][1] + bv);
                pk.y = pk_bf16(acc[mt][ntg][2] + bv, acc[mt][ntg][3] + bv);
                *(uint2*)(Vt + vrow + tloc + mt * 16 + quad * 4) = pk;
            }
        } else {
            const float qs = (col < 768) ? SCALE_LOG2E : 1.0f;
#pragma unroll
            for (int mt = 0; mt < 4; ++mt) {
#pragma unroll
                for (int i = 0; i < 4; ++i) {
                    const int row = bm + wM * 64 + mt * 16 + quad * 4 + i;
                    mixedOut[(size_t)row * E3_ + col] = f2bf((acc[mt][ntg][i] + bv) * qs);
                }
            }
        }
    }
}

// ---------------------------------------------------------------------------
// proj96: output projection, 256x96 exact-fill 3-phase (unchanged from R8).
// ---------------------------------------------------------------------------
__global__ __launch_bounds__(512, 2) void proj96(const unsigned short* __restrict__ A,
                                                 const unsigned short* __restrict__ Wt,
                                                 const float* __restrict__ bias,
                                                 float* __restrict__ out) {
    const int K = 768;
    const int NT = 12;
    __shared__ __align__(16) unsigned short lds[45568]; // A:2*16384 | B:2*6144 | scratch:512

    const int tid = threadIdx.x;
    const int lane = tid & 63;
    const int w = tid >> 6;            // 0..7
    const int quad = lane >> 4;
    const int l16 = lane & 15;
    const int wM = w >> 1;             // 0..3 (64-row slice)
    const int wN = w & 1;              // 0..1 (48-col slice)

    const int id = blockIdx.x;
    const int xcd = id & 7;
    const int slot = id >> 3;
    const int bx = slot >> 2;          // 0..7  (N tile, 96 cols)
    const int byl = slot & 3;
    const int bm = (xcd * 4 + byl) * 256;
    const int bn = bx * 96;

    const int jB2 = (w < 4) ? (8 + w) : -1;   // second B granule (or dummy)

    const int srcrow = lane >> 3;
    const int ssw = ((lane & 7) ^ (srcrow & 7)) << 3;
    const unsigned short* gaL = A + (size_t)(bm + srcrow) * K + ssw;
    const unsigned short* gbL = Wt + (size_t)(bn + srcrow) * K + ssw;
    unsigned short* ldsl = lds + lane * 8;

    const int rsw0 = ((quad) ^ (l16 & 7)) << 3;
    const int rsw1 = ((quad + 4) ^ (l16 & 7)) << 3;
    const unsigned short* rdA = lds + (wM * 64 + l16) * 64;
    const unsigned short* rdB = lds + 32768 + (wN * 48 + l16) * 64;

    short8 aF[4][2], bF[2];
    float4_ acc[4][3] = {};

#define PSTA(aj, toff, nb) gld_lds16(gaL + (size_t)(aj) * 6144 + (toff), \
                                     ldsl + (nb) * 16384 + (aj) * 512)
#define PSTB(j, toff, nb) { \
    const int _j = (j); \
    const unsigned short* _s = gbL + (size_t)(_j < 0 ? 0 : _j) * 6144 + (toff); \
    unsigned short* _d = (_j < 0) ? (ldsl + 45056) : (ldsl + 32768 + (nb) * 6144 + _j * 512); \
    gld_lds16(_s, _d); }
#define PLDA(buf) { \
    const unsigned short* _a = rdA + (buf) * 16384; \
    aF[0][0] = *(const short8*)(_a + rsw0);        aF[0][1] = *(const short8*)(_a + rsw1); \
    aF[1][0] = *(const short8*)(_a + 1024 + rsw0); aF[1][1] = *(const short8*)(_a + 1024 + rsw1); \
    aF[2][0] = *(const short8*)(_a + 2048 + rsw0); aF[2][1] = *(const short8*)(_a + 2048 + rsw1); \
    aF[3][0] = *(const short8*)(_a + 3072 + rsw0); aF[3][1] = *(const short8*)(_a + 3072 + rsw1); }
#define PLDB(buf, nt_) { \
    const unsigned short* _b = rdB + (buf) * 6144 + (nt_) * 1024; \
    bF[0] = *(const short8*)(_b + rsw0); \
    bF[1] = *(const short8*)(_b + rsw1); }
#define PMMA(nt_) \
    __builtin_amdgcn_s_setprio(1); \
    _Pragma("unroll") for (int mt = 0; mt < 4; ++mt) { \
        acc[mt][nt_] = __builtin_amdgcn_mfma_f32_16x16x32_bf16(aF[mt][0], bF[0], acc[mt][nt_], 0, 0, 0); \
        acc[mt][nt_] = __builtin_amdgcn_mfma_f32_16x16x32_bf16(aF[mt][1], bF[1], acc[mt][nt_], 0, 0, 0); } \
    __builtin_amdgcn_s_setprio(0);
#define PBAR __builtin_amdgcn_s_barrier()
#define PLGKM0 { asm volatile("s_waitcnt lgkmcnt(0)" ::: "memory"); __builtin_amdgcn_sched_barrier(0); }

    PSTA(w, 0, 0); PSTA(w + 8, 0, 0); PSTA(w + 16, 0, 0); PSTA(w + 24, 0, 0);
    PSTB(w, 0, 0); PSTB(jB2, 0, 0);
    asm volatile("s_waitcnt vmcnt(0)" ::: "memory");
    PBAR;

#pragma unroll 1
    for (int t = 0; t < NT - 1; ++t) {
        const int buf = t & 1;
        const int nb = buf ^ 1;
        const int toff = (t + 1) * 64;

        PLDA(buf); PLDB(buf, 0);
        PSTA(w, toff, nb); PSTA(w + 8, toff, nb); PSTA(w + 16, toff, nb);
        PBAR; PLGKM0; PMMA(0);
        asm volatile("s_waitcnt vmcnt(3)" ::: "memory"); PBAR;
        PLDB(buf, 1);
        PSTA(w + 24, toff, nb); PSTB(w, toff, nb); PSTB(jB2, toff, nb);
        PBAR; PLGKM0; PMMA(1);
        asm volatile("s_waitcnt vmcnt(3)" ::: "memory"); PBAR;
        PLDB(buf, 2);
        PBAR; PLGKM0; PMMA(2);
        asm volatile("s_waitcnt vmcnt(0)" ::: "memory"); PBAR;
    }
    {
        PLDA(1);
        PLDB(1, 0); PLGKM0; PMMA(0);
        PLDB(1, 1); PLGKM0; PMMA(1);
        PLDB(1, 2); PLGKM0; PMMA(2);
    }
#undef PSTA
#undef PSTB
#undef PLDA
#undef PLDB
#undef PMMA
#undef PBAR
#undef PLGKM0

#pragma unroll
    for (int nt = 0; nt < 3; ++nt) {
        const int col = bn + wN * 48 + nt * 16 + l16;
        const float bv = bias[col];
#pragma unroll
        for (int mt = 0; mt < 4; ++mt) {
#pragma unroll
            for (int i = 0; i < 4; ++i) {
                const int row = bm + wM * 64 + mt * 16 + quad * 4 + i;
                out[(size_t)row * E_ + col] = acc[mt][nt][i] + bv;
            }
        }
    }
}

// ---------------------------------------------------------------------------
// MFMA flash attention v12: R6 structure (Q-tile 128 — R9 proved smaller
// tiles lose via halved arithmetic intensity) + K/V LDS DOUBLE-BUFFER with
// ONE barrier per kv-tile (was 2). R8 counters: ~38% stall at 3 blocks/CU —
// barrier-lockstep resync. Iter t: write next tile's regs into buf^1
// (nobody reads it until after this iter's barrier), prefetch t+2 into
// regs, compute from buf[t&1], single __syncthreads. Race audit: reads of
// buf(X) finish before barrier(X); writes to buf(X) occur in iter X+1
// after that barrier. In-wave P round-trip unchanged (no barrier). LDS
// 51.7 KB -> still 3 blocks/CU. Arithmetic bit-identical to R6.
// ---------------------------------------------------------------------------
__global__ __launch_bounds__(256) void attn_mfma(const unsigned short* __restrict__ mixed,
                                                 const unsigned short* __restrict__ Vt,
                                                 unsigned short* __restrict__ ctx) {
    const int bh = blockIdx.x;
    const int b = bh / H_;
    const int h = bh % H_;
    const int q0 = blockIdx.y * 128;
    const int tid = threadIdx.x;
    const int lane = tid & 63;
    const int w = tid >> 6;
    const int quad = lane >> 4;
    const int l16 = lane & 15;

    // double-buffered K/V planes: [buf][plane p][64 rows][8 elems], stride 520
    __shared__ __align__(16) unsigned short Kl[2][8 * 520];
    __shared__ __align__(16) unsigned short Vl[2][8 * 520];
    __shared__ __align__(16) unsigned short Pl[4][32 * 72];
    unsigned short* pw = &Pl[w][0];

    short8 qf[2][2];
#pragma unroll
    for (int hh = 0; hh < 2; ++hh) {
        const size_t qrow = (size_t)(b * T_ + q0 + w * 32 + hh * 16 + l16) * E3_ + h * 64;
        qf[hh][0] = *(const short8*)(mixed + qrow + quad * 8);
        qf[hh][1] = *(const short8*)(mixed + qrow + 32 + quad * 8);
    }

    float4_ o[2][4] = {};
    float lps[2] = {0.0f, 0.0f};

    const size_t kbase = (size_t)(b * T_) * E3_ + E_ + h * 64;
    const size_t vtb = (size_t)bh * 64 * T_;

    const int srow = tid >> 3;
    const int sc = tid & 7;

    // ---- prologue: data(0) -> buf0 ; prefetch data(1) into regs ----
    {
        short8 a1 = *(const short8*)(mixed + kbase + (size_t)srow * E3_ + sc * 8);
        short8 a2 = *(const short8*)(mixed + kbase + (size_t)(srow + 32) * E3_ + sc * 8);
        short8 a3 = *(const short8*)(Vt + vtb + (size_t)srow * T_ + sc * 8);
        short8 a4 = *(const short8*)(Vt + vtb + (size_t)(srow + 32) * T_ + sc * 8);
        *(short8*)(&Kl[0][sc * 520 + srow * 8]) = a1;
        *(short8*)(&Kl[0][sc * 520 + (srow + 32) * 8]) = a2;
        *(short8*)(&Vl[0][sc * 520 + srow * 8]) = a3;
        *(short8*)(&Vl[0][sc * 520 + (srow + 32) * 8]) = a4;
    }
    short8 k1 = *(const short8*)(mixed + kbase + (size_t)(64 + srow) * E3_ + sc * 8);
    short8 k2 = *(const short8*)(mixed + kbase + (size_t)(64 + srow + 32) * E3_ + sc * 8);
    short8 v1 = *(const short8*)(Vt + vtb + (size_t)srow * T_ + 64 + sc * 8);
    short8 v2 = *(const short8*)(Vt + vtb + (size_t)(srow + 32) * T_ + 64 + sc * 8);
    __syncthreads();

#pragma unroll 1
    for (int t = 0; t < 16; ++t) {
        const int cur = t & 1;
        const unsigned short* kl = &Kl[cur][0];
        const unsigned short* vl = &Vl[cur][0];

        // publish next tile's data into the other buffer (read next iter)
        if (t + 1 < 16) {
            unsigned short* kd = &Kl[cur ^ 1][0];
            unsigned short* vd = &Vl[cur ^ 1][0];
            *(short8*)(&kd[sc * 520 + srow * 8]) = k1;
            *(short8*)(&kd[sc * 520 + (srow + 32) * 8]) = k2;
            *(short8*)(&vd[sc * 520 + srow * 8]) = v1;
            *(short8*)(&vd[sc * 520 + (srow + 32) * 8]) = v2;
        }
        // prefetch data(t+2) into regs (full iteration of latency cover)
        if (t + 2 < 16) {
            const int kn = (t + 2) * 64;
            k1 = *(const short8*)(mixed + kbase + (size_t)(kn + srow) * E3_ + sc * 8);
            k2 = *(const short8*)(mixed + kbase + (size_t)(kn + srow + 32) * E3_ + sc * 8);
            v1 = *(const short8*)(Vt + vtb + (size_t)srow * T_ + kn + sc * 8);
            v2 = *(const short8*)(Vt + vtb + (size_t)(srow + 32) * T_ + kn + sc * 8);
        }

        // S^T = K Q^T
        float4_ st[2][4];
#pragma unroll
        for (int nt = 0; nt < 4; ++nt) {
            const int key = nt * 16 + l16;
            short8 kf0 = *(const short8*)(&kl[quad * 520 + key * 8]);
            short8 kf1 = *(const short8*)(&kl[(4 + quad) * 520 + key * 8]);
#pragma unroll
            for (int hh = 0; hh < 2; ++hh) {
                float4_ z = {};
                z = __builtin_amdgcn_mfma_f32_16x16x32_bf16(kf0, qf[hh][0], z, 0, 0, 0);
                st[hh][nt] = __builtin_amdgcn_mfma_f32_16x16x32_bf16(kf1, qf[hh][1], z, 0, 0, 0);
            }
        }

        // p = exp2(s'); row sums; packed cvt -> ds_write_b64 per (hh, nt)
#pragma unroll
        for (int hh = 0; hh < 2; ++hh) {
#pragma unroll
            for (int nt = 0; nt < 4; ++nt) {
                const float p0 = __builtin_amdgcn_exp2f(st[hh][nt][0]);
                const float p1 = __builtin_amdgcn_exp2f(st[hh][nt][1]);
                const float p2 = __builtin_amdgcn_exp2f(st[hh][nt][2]);
                const float p3 = __builtin_amdgcn_exp2f(st[hh][nt][3]);
                uint2 pk;
                pk.x = pk_bf16(p0, p1);
                pk.y = pk_bf16(p2, p3);
                lps[hh] += (p0 + p1) + (p2 + p3);
                *(uint2*)(&pw[(hh * 16 + l16) * 72 + nt * 16 + quad * 4]) = pk;
            }
        }

        // P A-frags (in-wave DS ordering; no barrier needed)
        short8 pf[2][2];
#pragma unroll
        for (int hh = 0; hh < 2; ++hh) {
            pf[hh][0] = *(const short8*)(&pw[(hh * 16 + l16) * 72 + quad * 8]);
            pf[hh][1] = *(const short8*)(&pw[(hh * 16 + l16) * 72 + 32 + quad * 8]);
        }

        // O += P V
#pragma unroll
        for (int dt = 0; dt < 4; ++dt) {
            const int d = dt * 16 + l16;
            short8 vf0 = *(const short8*)(&vl[quad * 520 + d * 8]);
            short8 vf1 = *(const short8*)(&vl[(4 + quad) * 520 + d * 8]);
#pragma unroll
            for (int hh = 0; hh < 2; ++hh) {
                o[hh][dt] = __builtin_amdgcn_mfma_f32_16x16x32_bf16(pf[hh][0], vf0, o[hh][dt], 0, 0, 0);
                o[hh][dt] = __builtin_amdgcn_mfma_f32_16x16x32_bf16(pf[hh][1], vf1, o[hh][dt], 0, 0, 0);
            }
        }

        // ONE barrier: publishes buf^1 writes; next iter reads them.
        if (t + 1 < 16) __syncthreads();
    }

    // finalize (unchanged from R6)
#pragma unroll
    for (int hh = 0; hh < 2; ++hh) {
        float l = lps[hh];
        l += __shfl_xor(l, 16, 64);
        l += __shfl_xor(l, 32, 64);
        float4_ inv;
#pragma unroll
        for (int i = 0; i < 4; ++i)
            inv[i] = 1.0f / __shfl(l, quad * 4 + i, 16);
#pragma unroll
        for (int dt = 0; dt < 4; ++dt) {
#pragma unroll
            for (int i = 0; i < 4; ++i) {
                const float v = o[hh][dt][i] * inv[i];
                const size_t row = (size_t)(b * T_ + q0 + w * 32 + hh * 16 + quad * 4 + i);
                ctx[row * E_ + h * 64 + dt * 16 + l16] = f2bf(v);
            }
        }
    }
}

// ---------------------------------------------------------------------------
extern "C" void kernel_launch(void* const* d_in, const int* in_sizes, int n_in,
                              void* d_out, int out_size, void* d_ws, size_t ws_size,
                              hipStream_t stream) {
    const float* hs     = (const float*)d_in[0];
    const float* qkv_w  = (const float*)d_in[1];
    const float* qkv_b  = (const float*)d_in[2];
    const float* proj_w = (const float*)d_in[3];
    const float* proj_b = (const float*)d_in[4];
    float* out = (float*)d_out;

    unsigned short* hs_bf  = (unsigned short*)d_ws;                 // [8192][768]
    unsigned short* qkvwT  = hs_bf + (size_t)M_ * E_;               // [2304][768]
    unsigned short* projwT = qkvwT + (size_t)E3_ * E_;              // [768][768]
    unsigned short* mixed  = projwT + (size_t)E_ * E_;              // [8192][2304]
    unsigned short* Vt     = mixed + (size_t)M_ * E3_;              // [96*64][1024]
    unsigned short* ctx    = hs_bf;  // alias: hs_bf dead after GEMM1

    // 0) fused prepasses: cast + both weight transposes
    prep<<<8448, 256, 0, stream>>>(hs, qkv_w, proj_w, hs_bf, qkvwT, projwT);

    // 1) QKV projection -> mixed (Q scaled, K bf16) + Vt (V transposed)
    gemm288<<<256, 512, 0, stream>>>(hs_bf, qkvwT, qkv_b, mixed, Vt);
    // 2) attention -> ctx (bf16)  [Q-tile 128, K/V dbuf, 1 barrier/tile]
    attn_mfma<<<dim3(B_ * H_, T_ / 128), 256, 0, stream>>>(mixed, Vt, ctx);
    // 3) output projection -> out (fp32), 256x96 exact-fill 3-phase
    proj96<<<256, 512, 0, stream>>>(ctx, projwT, proj_b, out);
}

// Round 12
// 174.348 us; speedup vs baseline: 1.0571x; 1.0162x over previous
//
#include <hip/hip_runtime.h>
#include <hip/hip_bf16.h>

// Problem constants
#define B_ 8
#define T_ 1024
#define E_ 768
#define H_ 12
#define DH_ 64
#define E3_ 2304
#define M_ (B_ * T_)           // 8192 rows
// SCALE * log2(e): p = exp2(s * 0.125 * 1.4426950408889634)
// Applied to Q in gemm288's epilogue, NOT in the attention kernel.
#define SCALE_LOG2E 0.18033688011112042f

typedef __attribute__((ext_vector_type(8))) short short8;
typedef __attribute__((ext_vector_type(4))) float float4_;
typedef __attribute__((ext_vector_type(4))) unsigned short ushort4_;

__device__ __forceinline__ unsigned short f2bf(float f) {
    union { float f; unsigned int u; } v; v.f = f;
    unsigned int r = v.u + 0x7fffu + ((v.u >> 16) & 1u);
    return (unsigned short)(r >> 16);
}

// packed f32x2 -> bf16x2 (v_cvt_pk_bf16_f32, RNE — bit-identical to f2bf)
__device__ __forceinline__ unsigned int pk_bf16(float a, float b) {
    float2 t; t.x = a; t.y = b;
    union { __hip_bfloat162 h; unsigned int u; } cv;
    cv.h = __float22bfloat162_rn(t);
    return cv.u;
}

// async global->LDS, 16B per lane. LDS dest must be wave-uniform base + lane*16.
__device__ __forceinline__ void gld_lds16(const unsigned short* g, unsigned short* l) {
    __builtin_amdgcn_global_load_lds(
        (const __attribute__((address_space(1))) void*)g,
        (__attribute__((address_space(3))) void*)l,
        16, 0, 0);
}

// ---------------------------------------------------------------------------
// prep: cast section 1536 blocks x 4 float4/thread. R12 FIX: R11's indexing
// advanced base 16384/block but covered only 4096 -> OOB fault (the R11
// crash). Correct: i = (id*1024 + j*256 + tid)*4 ; 1536*4096 = |hs| exactly.
// ---------------------------------------------------------------------------
__global__ __launch_bounds__(256) void prep(const float* __restrict__ hs,
                                            const float* __restrict__ qkv_w,
                                            const float* __restrict__ proj_w,
                                            unsigned short* __restrict__ hs_bf,
                                            unsigned short* __restrict__ qkvwT,
                                            unsigned short* __restrict__ projwT) {
    __shared__ float tile[32][33];
    const int id = blockIdx.x;
    const int tid = threadIdx.x;
    if (id < 1536) {
#pragma unroll
        for (int j = 0; j < 4; ++j) {
            const int i = (id * 1024 + j * 256 + tid) * 4;
            float4_ v = *(const float4_*)(hs + i);
            ushort4_ o;
            o.x = f2bf(v.x); o.y = f2bf(v.y); o.z = f2bf(v.z); o.w = f2bf(v.w);
            *(ushort4_*)(hs_bf + i) = o;
        }
        return;
    }
    const float* W; unsigned short* Wt; int N, bx, by;
    if (id < 1536 + 1728) {
        const int t = id - 1536; W = qkv_w; Wt = qkvwT; N = E3_;
        bx = t % 72; by = t / 72;
    } else {
        const int t = id - 3264; W = proj_w; Wt = projwT; N = E_;
        bx = t % 24; by = t / 24;
    }
    const int k0 = by * 32, n0 = bx * 32;
    const int tx = tid & 31, ty = tid >> 5;
    for (int i = ty; i < 32; i += 8)
        tile[i][tx] = W[(size_t)(k0 + i) * N + n0 + tx];
    __syncthreads();
    for (int i = ty; i < 32; i += 8)
        Wt[(size_t)(n0 + i) * E_ + k0 + tx] = f2bf(tile[tx][i]);
}

// ---------------------------------------------------------------------------
// 256x288 3-phase GEMM for the QKV projection. R11/R12: removed the pre-MMA
// barrier in every phase (6 -> 3 barriers/K-tile). Audit: phase reads target
// buf[cur]; stages write buf[cur^1] (disjoint); cross-wave publication is
// carried by the END-of-phase vmcnt(3)+barrier chain (every consumed granule
// drained >=1 phase-end earlier in the producing wave's own stream; nh-sort
// keeps nh0 granules in the b0/b1 phase-1 slots). Per-wave lgkmcnt(0)+
// sched_barrier orders own ds_reads before MFMA. Arithmetic unchanged.
// ---------------------------------------------------------------------------
__global__ __launch_bounds__(512, 2) void gemm288(const unsigned short* __restrict__ A,
                                                  const unsigned short* __restrict__ Wt,
                                                  const float* __restrict__ bias,
                                                  unsigned short* __restrict__ mixedOut,
                                                  unsigned short* __restrict__ Vt) {
    const int K = 768;
    const int NT = 12;                 // K / 64
    __shared__ __align__(16) unsigned short lds[70144]; // A:2*16384 | B:2*18432 | scratch:512

    const int tid = threadIdx.x;
    const int lane = tid & 63;
    const int w = tid >> 6;            // 0..7
    const int quad = lane >> 4;
    const int l16 = lane & 15;
    const int wM = w >> 1;             // 0..3 (64-row slice)
    const int wN = w & 1;              // 0..1 (144-col slice)

    // grid 256 = 8 xcd * (8 bx * 4 byl), byl innermost
    const int id = blockIdx.x;
    const int xcd = id & 7;
    const int slot = id >> 3;          // 0..31
    const int bx = slot >> 2;          // 0..7
    const int byl = slot & 3;
    const int bm = (xcd * 4 + byl) * 256;
    const int bn = bx * 288;

    // ---- B granule ownership, sorted by nh third (wave-uniform) ----
    const int j4 = (w < 4) ? (w + 32) : 36;
    int kk0 = ((w % 18) / 6) * 64 + w;
    int kk1 = (((w + 8) % 18) / 6) * 64 + (w + 8);
    int kk2 = (((w + 16) % 18) / 6) * 64 + (w + 16);
    int kk3 = (((w + 24) % 18) / 6) * 64 + (w + 24);
    int kk4 = (j4 >= 36) ? (3 * 64 + 36) : (((j4 % 18) / 6) * 64 + j4);
#define CS_(a, b) { int _lo = min(a, b), _hi = max(a, b); a = _lo; b = _hi; }
    CS_(kk0, kk1) CS_(kk3, kk4) CS_(kk2, kk4) CS_(kk2, kk3) CS_(kk1, kk4)
    CS_(kk0, kk3) CS_(kk0, kk2) CS_(kk1, kk3) CS_(kk1, kk2)
#undef CS_
    const int b0 = kk0 & 63, b1 = kk1 & 63, b2 = kk2 & 63, b3 = kk3 & 63, b4 = kk4 & 63;

    // ---- staging constants ----
    const int srcrow = lane >> 3;                               // row within granule
    const int ssw = ((lane & 7) ^ (srcrow & 7)) << 3;           // swizzled src chunk (elems)
    const unsigned short* gaL = A + (size_t)(bm + srcrow) * K + ssw;
    const unsigned short* gbL = Wt + (size_t)(bn + srcrow) * K + ssw;
    unsigned short* ldsl = lds + lane * 8;

    // ---- fragment-read constants ----
    const int rsw0 = ((quad) ^ (l16 & 7)) << 3;                 // ks=0
    const int rsw1 = ((quad + 4) ^ (l16 & 7)) << 3;             // ks=1
    const unsigned short* rdA = lds + (wM * 64 + l16) * 64;
    const unsigned short* rdB = lds + 32768 + (wN * 144 + l16) * 64;

    short8 aF[4][2], bF[3][2];
    float4_ acc[4][9] = {};

#define STA_(aj, toff, bufA) gld_lds16(gaL + (size_t)(aj) * 6144 + (toff), (bufA) + (aj) * 512)
#define STB_(j, toff, bufB) { \
    const int _j = (j); \
    const unsigned short* _s = gbL + (size_t)(_j >= 36 ? 0 : _j) * 6144 + (toff); \
    unsigned short* _d = (_j >= 36) ? (ldsl + 69632) : ((bufB) + _j * 512); \
    gld_lds16(_s, _d); }

#define LDA_(buf) { \
    const unsigned short* _a = rdA + (buf) * 16384; \
    aF[0][0] = *(const short8*)(_a + rsw0);        aF[0][1] = *(const short8*)(_a + rsw1); \
    aF[1][0] = *(const short8*)(_a + 1024 + rsw0); aF[1][1] = *(const short8*)(_a + 1024 + rsw1); \
    aF[2][0] = *(const short8*)(_a + 2048 + rsw0); aF[2][1] = *(const short8*)(_a + 2048 + rsw1); \
    aF[3][0] = *(const short8*)(_a + 3072 + rsw0); aF[3][1] = *(const short8*)(_a + 3072 + rsw1); }

#define LDB_(buf, nh) { \
    const unsigned short* _b = rdB + (buf) * 18432 + (nh) * 3072; \
    bF[0][0] = *(const short8*)(_b + rsw0);        bF[0][1] = *(const short8*)(_b + rsw1); \
    bF[1][0] = *(const short8*)(_b + 1024 + rsw0); bF[1][1] = *(const short8*)(_b + 1024 + rsw1); \
    bF[2][0] = *(const short8*)(_b + 2048 + rsw0); bF[2][1] = *(const short8*)(_b + 2048 + rsw1); }

#define MMA_(nh) \
    __builtin_amdgcn_s_setprio(1); \
    _Pragma("unroll") for (int mt = 0; mt < 4; ++mt) \
    _Pragma("unroll") for (int nt = 0; nt < 3; ++nt) { \
        acc[mt][(nh) * 3 + nt] = __builtin_amdgcn_mfma_f32_16x16x32_bf16( \
            aF[mt][0], bF[nt][0], acc[mt][(nh) * 3 + nt], 0, 0, 0); \
        acc[mt][(nh) * 3 + nt] = __builtin_amdgcn_mfma_f32_16x16x32_bf16( \
            aF[mt][1], bF[nt][1], acc[mt][(nh) * 3 + nt], 0, 0, 0); } \
    __builtin_amdgcn_s_setprio(0);

#define BARRIER_ __builtin_amdgcn_s_barrier()
#define WLGKM0_ { asm volatile("s_waitcnt lgkmcnt(0)" ::: "memory"); __builtin_amdgcn_sched_barrier(0); }
#define WVM3_ asm volatile("s_waitcnt vmcnt(3)" ::: "memory")
#define WVM0_ asm volatile("s_waitcnt vmcnt(0)" ::: "memory")

    // ---- prologue: stage tile 0 (A first, then nh-sorted B; dummies last) ----
    {
        unsigned short* bufA = ldsl;            // buf0 A
        unsigned short* bufB = ldsl + 32768;    // buf0 B
        STA_(w, 0, bufA); STA_(w + 8, 0, bufA); STA_(w + 16, 0, bufA); STA_(w + 24, 0, bufA);
        STB_(b0, 0, bufB); STB_(b1, 0, bufB); STB_(b2, 0, bufB); STB_(b3, 0, bufB); STB_(b4, 0, bufB);
    }
    WVM3_; BARRIER_;

#pragma unroll 1
    for (int t = 0; t < NT - 1; ++t) {
        const int buf = t & 1;
        const int toff = (t + 1) * 64;
        unsigned short* bufA = ldsl + (buf ^ 1) * 16384;
        unsigned short* bufB = ldsl + 32768 + (buf ^ 1) * 18432;

        // phase 0 (nh=0) — no pre-MMA barrier (stages hit the other buffer)
        LDA_(buf); LDB_(buf, 0);
        STA_(w, toff, bufA); STA_(w + 8, toff, bufA); STA_(w + 16, toff, bufA);
        WLGKM0_; MMA_(0);
        WVM3_; BARRIER_;
        // phase 1 (nh=1)
        LDB_(buf, 1);
        STA_(w + 24, toff, bufA); STB_(b0, toff, bufB); STB_(b1, toff, bufB);
        WLGKM0_; MMA_(1);
        WVM3_; BARRIER_;
        // phase 2 (nh=2)
        LDB_(buf, 2);
        STB_(b2, toff, bufB); STB_(b3, toff, bufB); STB_(b4, toff, bufB);
        WLGKM0_; MMA_(2);
        WVM3_; BARRIER_;
    }
    // ---- peeled last tile (t = NT-1 = 11, buf = 1): no stages ----
    {
        LDA_(1); LDB_(1, 0);
        WLGKM0_; MMA_(0);
        WVM0_; BARRIER_;          // publish phase2(NT-2) stages before nh1/nh2 reads
        LDB_(1, 1);
        WLGKM0_; MMA_(1);
        LDB_(1, 2);
        WLGKM0_; MMA_(2);
    }
#undef STA_
#undef STB_
#undef LDA_
#undef LDB_
#undef MMA_

    // ---- epilogue ----
    // row = bm + wM*64 + mt*16 + quad*4 + i ; col = bn + wN*144 + ntg*16 + l16
    const int bb = bm >> 10;
    const int tloc = (bm & 1023) + wM * 64;
#pragma unroll
    for (int ntg = 0; ntg < 9; ++ntg) {
        const int col = bn + wN * 144 + ntg * 16 + l16;
        const float bv = bias[col];
        if (col >= 1536) {
            // V -> Vt[(b*12+h)*64 + d][1024], transposed
            const int n = col - 1536;
            const int h = n >> 6, d = n & 63;
            const size_t vrow = (size_t)((bb * H_ + h) * 64 + d) * T_;
#pragma unroll
            for (int mt = 0; mt < 4; ++mt) {
                uint2 pk;
                pk.x = pk_bf16(acc[mt][ntg][0] + bv, acc[mt][ntg][1] + bv);
                pk.y = pk_bf16(acc[mt][ntg][2] + bv, acc[mt][ntg][3] + bv);
                *(uint2*)(Vt + vrow + tloc + mt * 16 + quad * 4) = pk;
            }
        } else {
            const float qs = (col < 768) ? SCALE_LOG2E : 1.0f;
#pragma unroll
            for (int mt = 0; mt < 4; ++mt) {
#pragma unroll
                for (int i = 0; i < 4; ++i) {
                    const int row = bm + wM * 64 + mt * 16 + quad * 4 + i;
                    mixedOut[(size_t)row * E3_ + col] = f2bf((acc[mt][ntg][i] + bv) * qs);
                }
            }
        }
    }
}

// ---------------------------------------------------------------------------
// proj96: output projection, 256x96 exact-fill 3-phase. Pre-MMA barrier
// removed (same audit as gemm288; p2 ends with full vmcnt(0) drain).
// ---------------------------------------------------------------------------
__global__ __launch_bounds__(512, 2) void proj96(const unsigned short* __restrict__ A,
                                                 const unsigned short* __restrict__ Wt,
                                                 const float* __restrict__ bias,
                                                 float* __restrict__ out) {
    const int K = 768;
    const int NT = 12;
    __shared__ __align__(16) unsigned short lds[45568]; // A:2*16384 | B:2*6144 | scratch:512

    const int tid = threadIdx.x;
    const int lane = tid & 63;
    const int w = tid >> 6;            // 0..7
    const int quad = lane >> 4;
    const int l16 = lane & 15;
    const int wM = w >> 1;             // 0..3 (64-row slice)
    const int wN = w & 1;              // 0..1 (48-col slice)

    const int id = blockIdx.x;
    const int xcd = id & 7;
    const int slot = id >> 3;
    const int bx = slot >> 2;          // 0..7  (N tile, 96 cols)
    const int byl = slot & 3;
    const int bm = (xcd * 4 + byl) * 256;
    const int bn = bx * 96;

    const int jB2 = (w < 4) ? (8 + w) : -1;   // second B granule (or dummy)

    const int srcrow = lane >> 3;
    const int ssw = ((lane & 7) ^ (srcrow & 7)) << 3;
    const unsigned short* gaL = A + (size_t)(bm + srcrow) * K + ssw;
    const unsigned short* gbL = Wt + (size_t)(bn + srcrow) * K + ssw;
    unsigned short* ldsl = lds + lane * 8;

    const int rsw0 = ((quad) ^ (l16 & 7)) << 3;
    const int rsw1 = ((quad + 4) ^ (l16 & 7)) << 3;
    const unsigned short* rdA = lds + (wM * 64 + l16) * 64;
    const unsigned short* rdB = lds + 32768 + (wN * 48 + l16) * 64;

    short8 aF[4][2], bF[2];
    float4_ acc[4][3] = {};

#define PSTA(aj, toff, nb) gld_lds16(gaL + (size_t)(aj) * 6144 + (toff), \
                                     ldsl + (nb) * 16384 + (aj) * 512)
#define PSTB(j, toff, nb) { \
    const int _j = (j); \
    const unsigned short* _s = gbL + (size_t)(_j < 0 ? 0 : _j) * 6144 + (toff); \
    unsigned short* _d = (_j < 0) ? (ldsl + 45056) : (ldsl + 32768 + (nb) * 6144 + _j * 512); \
    gld_lds16(_s, _d); }
#define PLDA(buf) { \
    const unsigned short* _a = rdA + (buf) * 16384; \
    aF[0][0] = *(const short8*)(_a + rsw0);        aF[0][1] = *(const short8*)(_a + rsw1); \
    aF[1][0] = *(const short8*)(_a + 1024 + rsw0); aF[1][1] = *(const short8*)(_a + 1024 + rsw1); \
    aF[2][0] = *(const short8*)(_a + 2048 + rsw0); aF[2][1] = *(const short8*)(_a + 2048 + rsw1); \
    aF[3][0] = *(const short8*)(_a + 3072 + rsw0); aF[3][1] = *(const short8*)(_a + 3072 + rsw1); }
#define PLDB(buf, nt_) { \
    const unsigned short* _b = rdB + (buf) * 6144 + (nt_) * 1024; \
    bF[0] = *(const short8*)(_b + rsw0); \
    bF[1] = *(const short8*)(_b + rsw1); }
#define PMMA(nt_) \
    __builtin_amdgcn_s_setprio(1); \
    _Pragma("unroll") for (int mt = 0; mt < 4; ++mt) { \
        acc[mt][nt_] = __builtin_amdgcn_mfma_f32_16x16x32_bf16(aF[mt][0], bF[0], acc[mt][nt_], 0, 0, 0); \
        acc[mt][nt_] = __builtin_amdgcn_mfma_f32_16x16x32_bf16(aF[mt][1], bF[1], acc[mt][nt_], 0, 0, 0); } \
    __builtin_amdgcn_s_setprio(0);
#define PBAR __builtin_amdgcn_s_barrier()
#define PLGKM0 { asm volatile("s_waitcnt lgkmcnt(0)" ::: "memory"); __builtin_amdgcn_sched_barrier(0); }

    PSTA(w, 0, 0); PSTA(w + 8, 0, 0); PSTA(w + 16, 0, 0); PSTA(w + 24, 0, 0);
    PSTB(w, 0, 0); PSTB(jB2, 0, 0);
    asm volatile("s_waitcnt vmcnt(0)" ::: "memory");
    PBAR;

#pragma unroll 1
    for (int t = 0; t < NT - 1; ++t) {
        const int buf = t & 1;
        const int nb = buf ^ 1;
        const int toff = (t + 1) * 64;

        // phase 0 (nt=0) — no pre-MMA barrier
        PLDA(buf); PLDB(buf, 0);
        PSTA(w, toff, nb); PSTA(w + 8, toff, nb); PSTA(w + 16, toff, nb);
        PLGKM0; PMMA(0);
        asm volatile("s_waitcnt vmcnt(3)" ::: "memory"); PBAR;
        // phase 1 (nt=1)
        PLDB(buf, 1);
        PSTA(w + 24, toff, nb); PSTB(w, toff, nb); PSTB(jB2, toff, nb);
        PLGKM0; PMMA(1);
        asm volatile("s_waitcnt vmcnt(3)" ::: "memory"); PBAR;
        // phase 2 (nt=2) — no stages; full drain so t+1.p0 reads are safe
        PLDB(buf, 2);
        PLGKM0; PMMA(2);
        asm volatile("s_waitcnt vmcnt(0)" ::: "memory"); PBAR;
    }
    {
        PLDA(1);
        PLDB(1, 0); PLGKM0; PMMA(0);
        PLDB(1, 1); PLGKM0; PMMA(1);
        PLDB(1, 2); PLGKM0; PMMA(2);
    }
#undef PSTA
#undef PSTB
#undef PLDA
#undef PLDB
#undef PMMA
#undef PBAR
#undef PLGKM0

#pragma unroll
    for (int nt = 0; nt < 3; ++nt) {
        const int col = bn + wN * 48 + nt * 16 + l16;
        const float bv = bias[col];
#pragma unroll
        for (int mt = 0; mt < 4; ++mt) {
#pragma unroll
            for (int i = 0; i < 4; ++i) {
                const int row = bm + wM * 64 + mt * 16 + quad * 4 + i;
                out[(size_t)row * E_ + col] = acc[mt][nt][i] + bv;
            }
        }
    }
}

// ---------------------------------------------------------------------------
// MFMA flash attention — EXACT R6/R8 version (44.2-44.6 us, reproduced 3x).
// At its structural local floor (R5/R7/R9/R10 alternatives all regressed).
// ---------------------------------------------------------------------------
__global__ __launch_bounds__(256) void attn_mfma(const unsigned short* __restrict__ mixed,
                                                 const unsigned short* __restrict__ Vt,
                                                 unsigned short* __restrict__ ctx) {
    const int bh = blockIdx.x;
    const int b = bh / H_;
    const int h = bh % H_;
    const int q0 = blockIdx.y * 128;
    const int tid = threadIdx.x;
    const int lane = tid & 63;
    const int w = tid >> 6;
    const int quad = lane >> 4;
    const int l16 = lane & 15;

    __shared__ __align__(16) unsigned short Kl[8 * 520];
    __shared__ __align__(16) unsigned short Vl[8 * 520];
    __shared__ __align__(16) unsigned short Pl[4][32 * 72];
    unsigned short* pw = &Pl[w][0];

    short8 qf[2][2];
#pragma unroll
    for (int hh = 0; hh < 2; ++hh) {
        const size_t qrow = (size_t)(b * T_ + q0 + w * 32 + hh * 16 + l16) * E3_ + h * 64;
        qf[hh][0] = *(const short8*)(mixed + qrow + quad * 8);
        qf[hh][1] = *(const short8*)(mixed + qrow + 32 + quad * 8);
    }

    float4_ o[2][4] = {};
    float lps[2] = {0.0f, 0.0f};

    const size_t kbase = (size_t)(b * T_) * E3_ + E_ + h * 64;
    const size_t vtb = (size_t)bh * 64 * T_;

    const int srow = tid >> 3;
    const int sc = tid & 7;

    short8 k1 = *(const short8*)(mixed + kbase + (size_t)srow * E3_ + sc * 8);
    short8 k2 = *(const short8*)(mixed + kbase + (size_t)(srow + 32) * E3_ + sc * 8);
    short8 v1 = *(const short8*)(Vt + vtb + (size_t)srow * T_ + sc * 8);
    short8 v2 = *(const short8*)(Vt + vtb + (size_t)(srow + 32) * T_ + sc * 8);

    for (int kv0 = 0; kv0 < T_; kv0 += 64) {
        __syncthreads();
        *(short8*)(&Kl[sc * 520 + srow * 8]) = k1;
        *(short8*)(&Kl[sc * 520 + (srow + 32) * 8]) = k2;
        *(short8*)(&Vl[sc * 520 + srow * 8]) = v1;
        *(short8*)(&Vl[sc * 520 + (srow + 32) * 8]) = v2;
        __syncthreads();

        if (kv0 + 64 < T_) {
            const int kn = kv0 + 64;
            k1 = *(const short8*)(mixed + kbase + (size_t)(kn + srow) * E3_ + sc * 8);
            k2 = *(const short8*)(mixed + kbase + (size_t)(kn + srow + 32) * E3_ + sc * 8);
            v1 = *(const short8*)(Vt + vtb + (size_t)srow * T_ + kn + sc * 8);
            v2 = *(const short8*)(Vt + vtb + (size_t)(srow + 32) * T_ + kn + sc * 8);
        }

        float4_ st[2][4];
#pragma unroll
        for (int nt = 0; nt < 4; ++nt) {
            const int key = nt * 16 + l16;
            short8 kf0 = *(const short8*)(&Kl[quad * 520 + key * 8]);
            short8 kf1 = *(const short8*)(&Kl[(4 + quad) * 520 + key * 8]);
#pragma unroll
            for (int hh = 0; hh < 2; ++hh) {
                float4_ z = {};
                z = __builtin_amdgcn_mfma_f32_16x16x32_bf16(kf0, qf[hh][0], z, 0, 0, 0);
                st[hh][nt] = __builtin_amdgcn_mfma_f32_16x16x32_bf16(kf1, qf[hh][1], z, 0, 0, 0);
            }
        }

#pragma unroll
        for (int hh = 0; hh < 2; ++hh) {
#pragma unroll
            for (int nt = 0; nt < 4; ++nt) {
                const float p0 = __builtin_amdgcn_exp2f(st[hh][nt][0]);
                const float p1 = __builtin_amdgcn_exp2f(st[hh][nt][1]);
                const float p2 = __builtin_amdgcn_exp2f(st[hh][nt][2]);
                const float p3 = __builtin_amdgcn_exp2f(st[hh][nt][3]);
                uint2 pk;
                pk.x = pk_bf16(p0, p1);
                pk.y = pk_bf16(p2, p3);
                lps[hh] += (p0 + p1) + (p2 + p3);
                *(uint2*)(&pw[(hh * 16 + l16) * 72 + nt * 16 + quad * 4]) = pk;
            }
        }

        short8 pf[2][2];
#pragma unroll
        for (int hh = 0; hh < 2; ++hh) {
            pf[hh][0] = *(const short8*)(&pw[(hh * 16 + l16) * 72 + quad * 8]);
            pf[hh][1] = *(const short8*)(&pw[(hh * 16 + l16) * 72 + 32 + quad * 8]);
        }

#pragma unroll
        for (int dt = 0; dt < 4; ++dt) {
            const int d = dt * 16 + l16;
            short8 vf0 = *(const short8*)(&Vl[quad * 520 + d * 8]);
            short8 vf1 = *(const short8*)(&Vl[(4 + quad) * 520 + d * 8]);
#pragma unroll
            for (int hh = 0; hh < 2; ++hh) {
                o[hh][dt] = __builtin_amdgcn_mfma_f32_16x16x32_bf16(pf[hh][0], vf0, o[hh][dt], 0, 0, 0);
                o[hh][dt] = __builtin_amdgcn_mfma_f32_16x16x32_bf16(pf[hh][1], vf1, o[hh][dt], 0, 0, 0);
            }
        }
    }

#pragma unroll
    for (int hh = 0; hh < 2; ++hh) {
        float l = lps[hh];
        l += __shfl_xor(l, 16, 64);
        l += __shfl_xor(l, 32, 64);
        float4_ inv;
#pragma unroll
        for (int i = 0; i < 4; ++i)
            inv[i] = 1.0f / __shfl(l, quad * 4 + i, 16);
#pragma unroll
        for (int dt = 0; dt < 4; ++dt) {
#pragma unroll
            for (int i = 0; i < 4; ++i) {
                const float v = o[hh][dt][i] * inv[i];
                const size_t row = (size_t)(b * T_ + q0 + w * 32 + hh * 16 + quad * 4 + i);
                ctx[row * E_ + h * 64 + dt * 16 + l16] = f2bf(v);
            }
        }
    }
}

// ---------------------------------------------------------------------------
extern "C" void kernel_launch(void* const* d_in, const int* in_sizes, int n_in,
                              void* d_out, int out_size, void* d_ws, size_t ws_size,
                              hipStream_t stream) {
    const float* hs     = (const float*)d_in[0];
    const float* qkv_w  = (const float*)d_in[1];
    const float* qkv_b  = (const float*)d_in[2];
    const float* proj_w = (const float*)d_in[3];
    const float* proj_b = (const float*)d_in[4];
    float* out = (float*)d_out;

    unsigned short* hs_bf  = (unsigned short*)d_ws;                 // [8192][768]
    unsigned short* qkvwT  = hs_bf + (size_t)M_ * E_;               // [2304][768]
    unsigned short* projwT = qkvwT + (size_t)E3_ * E_;              // [768][768]
    unsigned short* mixed  = projwT + (size_t)E_ * E_;              // [8192][2304]
    unsigned short* Vt     = mixed + (size_t)M_ * E3_;              // [96*64][1024]
    unsigned short* ctx    = hs_bf;  // alias: hs_bf dead after GEMM1

    // 0) fused prepasses: cast (1536 blk, fixed indexing) + weight transposes
    prep<<<3840, 256, 0, stream>>>(hs, qkv_w, proj_w, hs_bf, qkvwT, projwT);

    // 1) QKV projection -> mixed (Q scaled, K bf16) + Vt (V transposed)
    gemm288<<<256, 512, 0, stream>>>(hs_bf, qkvwT, qkv_b, mixed, Vt);
    // 2) attention -> ctx (bf16)  [R6 final: 44.2-44.6 us, 3x reproduced]
    attn_mfma<<<dim3(B_ * H_, T_ / 128), 256, 0, stream>>>(mixed, Vt, ctx);
    // 3) output projection -> out (fp32), 256x96, 3 barriers/tile
    proj96<<<256, 512, 0, stream>>>(ctx, projwT, proj_b, out);
}